// Round 5
// baseline (171.507 us; speedup 1.0000x reference)
//
#include <hip/hip_runtime.h>
#include <math.h>

// Problem constants
#define Bn   4
#define Cc   64
#define Hh   128
#define Ww   128
#define Oo   64
#define HW   16384
#define NPAR 27

// Workspace layout (float offsets)
#define WB2_OFF 0        // bf16 AT2[t][cc][mt2][lane64][8] = 36864 shorts
#define WB_OFF  18432    // bf16 ATd[t][h][mt4][lane64][8]  = 36864 shorts
#define PAR_OFF 36864    // f32 par[B][27][HW]

typedef __attribute__((ext_vector_type(8))) short bf16x8;
typedef __attribute__((ext_vector_type(4))) short s16x4;
typedef __attribute__((ext_vector_type(4))) float f32x4;
typedef __attribute__((ext_vector_type(2), aligned(4))) float f32x2u;

__device__ __forceinline__ short f2bf(float f) {
    unsigned u = __builtin_bit_cast(unsigned, f);
    u += 0x7FFFu + ((u >> 16) & 1u);        // RNE
    return (short)(u >> 16);
}

// ---------------------------------------------------------------------------
// prep: pre-transpose weights into MFMA A-fragment order (coalesced dwordx4
// reads in the main kernels). K reordered tap-major; see r4 comment.
// ---------------------------------------------------------------------------
__global__ void prep_weights(const float* __restrict__ w_off,
                             const float* __restrict__ w_mod,
                             const float* __restrict__ w_reg,
                             float* __restrict__ ws) {
    int i = blockIdx.x * 256 + threadIdx.x;
    short* at2 = (short*)(ws + WB2_OFF);
    short* atd = (short*)(ws + WB_OFF);
    if (i < 36864) {
        int j = i & 7, l = (i >> 3) & 63, mt = (i >> 9) & 1, cc = (i >> 10) & 3, t = i >> 12;
        int lm = l & 15, quad = l >> 4;
        int row = mt * 16 + lm;
        int c = cc * 32 + quad * 8 + j;
        float v = 0.f;
        if (row < 18)      v = w_off[row * 1152 + c * 9 + t];
        else if (row < 27) v = w_mod[(row - 18) * 1152 + c * 9 + t];
        at2[i] = f2bf(v);
    } else if (i < 73728) {
        int e = i - 36864;
        int j = e & 7, l = (e >> 3) & 63, mt = (e >> 9) & 3, h = (e >> 11) & 1, t = e >> 12;
        int lm = l & 15, quad = l >> 4;
        int o = mt * 16 + lm;
        int c = h * 32 + quad * 8 + j;
        atd[e] = f2bf(w_reg[o * 576 + c * 9 + t]);
    }
}

// ---------------------------------------------------------------------------
// conv_mfma (unchanged from r4): barrier-free direct conv, bf16 channel-inner
// window [pos][128ch+8], one ds_read_b128 per B-fragment, coalesced A.
// 39.2KB LDS -> 4 blocks/CU.
// ---------------------------------------------------------------------------
#define CPSTR 136   // bf16 elems per position: 128 ch + 8 pad

__global__ __launch_bounds__(256, 4)
void conv_mfma(const float* __restrict__ x, const float* __restrict__ g,
               const float* __restrict__ ws_,
               const float* __restrict__ b_off, const float* __restrict__ b_mod,
               float* __restrict__ parw) {
    __shared__ __align__(16) short Wd[144 * CPSTR];   // 39168 B

    const int tid = threadIdx.x;
    const int l = tid & 63, lm = l & 15, quad = l >> 4;
    const int w = __builtin_amdgcn_readfirstlane(tid >> 6);   // wave = pixel row
    const int b = blockIdx.z;
    const int ho0 = blockIdx.y * 4, wo0 = blockIdx.x * 16;
    const int row_base = ho0 - 1;     // may be -1: halo rows zero-filled
    const int col_base = wo0 - 4;     // 4-aligned; halo cols zero-filled

    const short* at2 = (const short*)(ws_ + WB2_OFF);
    const float* xb = x + ((size_t)(b * Cc) << 14);
    const float* gb = g + ((size_t)(b * Cc) << 14);

    for (int s = tid; s < 1152; s += 256) {
        int pq = s >> 5, cq = s & 31;
        int r = pq / 6, c4 = (pq - r * 6) * 4;
        int row = row_base + r, col = col_base + c4;
        bool ok = ((unsigned)row < 128u) && ((unsigned)col < 128u);
        f32x4 v0, v1, v2, v3;
        {
            int ch = cq * 4;
            const float* p0 = (ch < Cc) ? (xb + ((size_t)ch << 14)) : (gb + ((size_t)(ch - Cc) << 14));
            const float* p1 = (ch + 1 < Cc) ? (xb + ((size_t)(ch + 1) << 14)) : (gb + ((size_t)(ch + 1 - Cc) << 14));
            const float* p2 = (ch + 2 < Cc) ? (xb + ((size_t)(ch + 2) << 14)) : (gb + ((size_t)(ch + 2 - Cc) << 14));
            const float* p3 = (ch + 3 < Cc) ? (xb + ((size_t)(ch + 3) << 14)) : (gb + ((size_t)(ch + 3 - Cc) << 14));
            f32x4 zz = {0.f, 0.f, 0.f, 0.f};
            size_t off = ((size_t)(row << 7) + col);
            v0 = ok ? *(const f32x4*)(p0 + off) : zz;
            v1 = ok ? *(const f32x4*)(p1 + off) : zz;
            v2 = ok ? *(const f32x4*)(p2 + off) : zz;
            v3 = ok ? *(const f32x4*)(p3 + off) : zz;
        }
#pragma unroll
        for (int p = 0; p < 4; p++) {
            s16x4 o4 = { f2bf(v0[p]), f2bf(v1[p]), f2bf(v2[p]), f2bf(v3[p]) };
            *(s16x4*)&Wd[(r * 24 + c4 + p) * CPSTR + cq * 4] = o4;
        }
    }
    __syncthreads();   // the ONLY barrier

    f32x4 acc0 = {0.f, 0.f, 0.f, 0.f}, acc1 = {0.f, 0.f, 0.f, 0.f};
#pragma unroll
    for (int t = 0; t < 9; t++) {
        int dy = t / 3, dx = t - dy * 3;
        int pos = (w + dy) * 24 + (lm + dx + 3);    // in-window coords, no masks
#pragma unroll
        for (int cc = 0; cc < 4; cc++) {
            bf16x8 bfr = *(const bf16x8*)&Wd[pos * CPSTR + cc * 32 + quad * 8];
            bf16x8 a0 = *(const bf16x8*)(at2 + t * 4096 + cc * 1024 + l * 8);
            bf16x8 a1 = *(const bf16x8*)(at2 + t * 4096 + cc * 1024 + 512 + l * 8);
            acc0 = __builtin_amdgcn_mfma_f32_16x16x32_bf16(a0, bfr, acc0, 0, 0, 0);
            acc1 = __builtin_amdgcn_mfma_f32_16x16x32_bf16(a1, bfr, acc1, 0, 0, 0);
        }
    }

    // Epilogue: D[row j][col lm] -> par channels, fused bias/coords/sigmoid
    const int ho = ho0 + w, wo = wo0 + lm;
    const int pix = (ho << 7) + wo;
    float* par = parw + (size_t)b * NPAR * HW + pix;
#pragma unroll
    for (int mt = 0; mt < 2; mt++) {
        f32x4 a = mt ? acc1 : acc0;
#pragma unroll
        for (int reg = 0; reg < 4; reg++) {
            int j = mt * 16 + quad * 4 + reg;
            float v = a[reg];
            if (j < 18) {
                int k = j >> 1;
                float vb = v + b_off[j];
                if (j & 1) par[(size_t)(9 + k) * HW] = vb + (float)(k - (k / 3) * 3 + wo - 1);
                else       par[(size_t)k * HW]       = vb + (float)(k / 3 + ho - 1);
            } else if (j < 27) {
                int k = j - 18;
                par[(size_t)(18 + k) * HW] = 2.f / (1.f + __expf(-(v + b_mod[k])));
            }
        }
    }
}

// ---------------------------------------------------------------------------
// deform_mfma round 5: occupancy fix. r4 counters: Occupancy 23%, LDS=48.6KB
// -> 3 blocks/CU, and 1024 blocks over 256 CUs at 3/CU leaves a 256-block
// straggler wave (built-in 25%-duty tail). In the r4 partitioning each lane
// only consumes params of ITS OWN pixel (s = t*64 + w*16 + lm), so the
// sIdx/sWt LDS arrays (14KB) are pure redistribution overhead: compute the
// bilinear params PER-LANE into registers instead (bit-identical math, 4x
// redundant VALU on a 16%-busy pipe). LDS 48.6 -> 34.6KB -> 4 blocks/CU,
// grid 1024 = exactly one full resident wave, no tail. launch_bounds(256,4)
// caps VGPR at 128 (est ~113). Slow path fully unrolled so the register
// arrays stay compile-time-indexed (no scratch).
// ---------------------------------------------------------------------------
#define DPSTR 36   // f32 per position: 32 ch + 4 pad

__global__ __launch_bounds__(256, 4)
void deform_mfma(const float* __restrict__ x, const float* __restrict__ ws_,
                 const float* __restrict__ par_base, float* __restrict__ out) {
    __shared__ __align__(16) float Xw[240 * DPSTR];   // 34560 B
    __shared__ int sOk;

    const int tid = threadIdx.x;
    const int l = tid & 63, lm = l & 15, quad = l >> 4;
    const int w = __builtin_amdgcn_readfirstlane(tid >> 6);   // wave = pixel row
    const int b = blockIdx.z;

    const int ho0 = blockIdx.y * 4, wo0 = blockIdx.x * 16;
    const int rb = min(max(ho0 - 3, 0), 128 - 10);
    const int cb = min(max(wo0 - 4, 0), 128 - 24);    // 4-aligned

    const float* par = par_base + (size_t)b * NPAR * HW;
    const short* atd = (const short*)(ws_ + WB_OFF);
    const float* xb  = x + ((size_t)(b * Cc) << 14);

    if (tid == 0) sOk = 1;
    __syncthreads();

    // Per-lane bilinear params for own pixel, all 9 taps -> registers.
    const int pix = ((ho0 + w) << 7) + (wo0 + lm);
    int   rIdx[9];                        // cy0 | cy1<<8 | bx2<<16
    float rw0[9], rw1[9], rw2[9], rw3[9]; // folded corner weights
    int okAll = 1;
#pragma unroll
    for (int k = 0; k < 9; k++) {
        float py = par[(size_t)k * HW + pix];
        float px = par[(size_t)(9 + k) * HW + pix];
        float m  = par[(size_t)(18 + k) * HW + pix];
        float fy = floorf(py), fx = floorf(px);
        int y0 = (int)fy, x0 = (int)fx;
        int y1 = y0 + 1;
        float wy1 = py - fy, wx1 = px - fx;
        float wy0 = 1.f - wy1, wx0 = 1.f - wx1;
        bool vy0 = (unsigned)y0 < 128u, vy1 = (unsigned)y1 < 128u;
        bool vx0 = (unsigned)x0 < 128u, vx1 = (unsigned)(x0 + 1) < 128u;
        int cy0 = min(max(y0, 0), 127), cy1 = min(max(y1, 0), 127);
        int bx2 = min(max(x0, 0), 126);
        bool sel_lo = (x0 < 0), sel_hi = (x0 > 126);
        float w00 = (vy0 && vx0) ? wy0 * wx0 * m : 0.f;
        float w01 = (vy0 && vx1) ? wy0 * wx1 * m : 0.f;
        float w10 = (vy1 && vx0) ? wy1 * wx0 * m : 0.f;
        float w11 = (vy1 && vx1) ? wy1 * wx1 * m : 0.f;
        // fold boundary handling into pair weights: wa->[bx2], wb->[bx2+1]
        rw0[k] = sel_lo ? w01 : (sel_hi ? 0.f : w00);
        rw1[k] = sel_hi ? w00 : (sel_lo ? 0.f : w01);
        rw2[k] = sel_lo ? w11 : (sel_hi ? 0.f : w10);
        rw3[k] = sel_hi ? w10 : (sel_lo ? 0.f : w11);
        rIdx[k] = cy0 | (cy1 << 8) | (bx2 << 16);
        bool in = ((unsigned)(cy0 - rb) <= 9u) &&
                  ((unsigned)(cy1 - rb) <= 9u) &&
                  ((unsigned)(bx2 - cb) <= 22u);
        okAll &= (int)in;
    }
    if (!__all(okAll)) sOk = 0;

    // window stage: 60 pos-quads x 8 ch-quads; 4 f32x4 loads + transpose +
    // 4 f32x4 ds_writes, ch-inner. All positions in-image (bases clamped).
    auto STAGE = [&](int h) {
        for (int s = tid; s < 480; s += 256) {
            int pq = s >> 3, cq = s & 7;
            int r = pq / 6, c4 = (pq - r * 6) * 4;
            size_t off = (size_t)((rb + r) << 7) + cb + c4;
            f32x4 v0 = *(const f32x4*)(xb + ((size_t)(h * 32 + cq * 4 + 0) << 14) + off);
            f32x4 v1 = *(const f32x4*)(xb + ((size_t)(h * 32 + cq * 4 + 1) << 14) + off);
            f32x4 v2 = *(const f32x4*)(xb + ((size_t)(h * 32 + cq * 4 + 2) << 14) + off);
            f32x4 v3 = *(const f32x4*)(xb + ((size_t)(h * 32 + cq * 4 + 3) << 14) + off);
#pragma unroll
            for (int p = 0; p < 4; p++) {
                f32x4 o4 = { v0[p], v1[p], v2[p], v3[p] };
                *(f32x4*)&Xw[(r * 24 + c4 + p) * DPSTR + cq * 4] = o4;
            }
        }
    };

    STAGE(0);
    __syncthreads();
    const int fast = sOk;                 // block-uniform

    f32x4 acc[4];
#pragma unroll
    for (int mt = 0; mt < 4; mt++) acc[mt] = (f32x4){0.f, 0.f, 0.f, 0.f};

    auto T_LOOP = [&](int h) {
#pragma unroll
        for (int t = 0; t < 9; t++) {
            int e = rIdx[t];
            int tx = (e >> 16) - cb;
            int ia = ((e & 255) - rb) * 24 + tx;
            int ib = (((e >> 8) & 255) - rb) * 24 + tx;
            float4 wv = make_float4(rw0[t], rw1[t], rw2[t], rw3[t]);
            const float* pa = &Xw[ia * DPSTR + quad * 8];
            const float* pb = &Xw[ib * DPSTR + quad * 8];
            union { short s8[8]; bf16x8 v; } u;
#pragma unroll
            for (int hf = 0; hf < 2; hf++) {
                f32x4 p00 = *(const f32x4*)(pa + hf * 4);
                f32x4 p01 = *(const f32x4*)(pa + DPSTR + hf * 4);
                f32x4 p10 = *(const f32x4*)(pb + hf * 4);
                f32x4 p11 = *(const f32x4*)(pb + DPSTR + hf * 4);
#pragma unroll
                for (int j = 0; j < 4; j++)
                    u.s8[hf * 4 + j] = f2bf(wv.x * p00[j] + wv.y * p01[j] +
                                            wv.z * p10[j] + wv.w * p11[j]);
            }
#pragma unroll
            for (int mt = 0; mt < 4; mt++) {
                bf16x8 a = *(const bf16x8*)(atd + t * 4096 + h * 2048 + mt * 512 + l * 8);
                acc[mt] = __builtin_amdgcn_mfma_f32_16x16x32_bf16(a, u.v, acc[mt], 0, 0, 0);
            }
        }
    };

    if (fast) {
        T_LOOP(0);
        __syncthreads();      // all waves done reading half 0
        STAGE(1);
        __syncthreads();
        T_LOOP(1);
    } else {
        // rare fallback: offsets beyond halo -> global bilinear gather
#pragma unroll
        for (int h = 0; h < 2; h++) {
#pragma unroll
            for (int t = 0; t < 9; t++) {
                int e = rIdx[t];
                int idx0 = ((e & 255) << 7) + (e >> 16);
                int idx1 = (((e >> 8) & 255) << 7) + (e >> 16);
                float4 wv = make_float4(rw0[t], rw1[t], rw2[t], rw3[t]);
                union { short s8[8]; bf16x8 v; } u;
#pragma unroll
                for (int j = 0; j < 8; j++) {
                    int c = h * 32 + quad * 8 + j;
                    const float* xc = xb + ((size_t)c << 14);
                    f32x2u q0 = *(const f32x2u*)(xc + idx0);
                    f32x2u q1 = *(const f32x2u*)(xc + idx1);
                    u.s8[j] = f2bf(wv.x * q0.x + wv.y * q0.y + wv.z * q1.x + wv.w * q1.y);
                }
#pragma unroll
                for (int mt = 0; mt < 4; mt++) {
                    bf16x8 a = *(const bf16x8*)(atd + t * 4096 + h * 2048 + mt * 512 + l * 8);
                    acc[mt] = __builtin_amdgcn_mfma_f32_16x16x32_bf16(a, u.v, acc[mt], 0, 0, 0);
                }
            }
        }
    }

    // Epilogue: D[row=quad*4+reg][col=lm]; o = mt*16+row, pixel = (ho0+w, wo0+lm)
    const int wo = wo0 + lm, ho = ho0 + w;
#pragma unroll
    for (int mt = 0; mt < 4; mt++) {
        float* op = out + ((size_t)(b * Oo + mt * 16 + quad * 4) << 14) + (ho << 7) + wo;
#pragma unroll
        for (int reg = 0; reg < 4; reg++)
            op[(size_t)reg << 14] = acc[mt][reg];
    }
}

// ---------------------------------------------------------------------------
extern "C" void kernel_launch(void* const* d_in, const int* in_sizes, int n_in,
                              void* d_out, int out_size, void* d_ws, size_t ws_size,
                              hipStream_t stream) {
    const float* x     = (const float*)d_in[0];
    const float* guide = (const float*)d_in[1];
    const float* w_off = (const float*)d_in[2];
    const float* b_off = (const float*)d_in[3];
    const float* w_mod = (const float*)d_in[4];
    const float* b_mod = (const float*)d_in[5];
    const float* w_reg = (const float*)d_in[6];
    float* out = (float*)d_out;
    float* ws  = (float*)d_ws;

    hipLaunchKernelGGL(prep_weights, dim3((73728 + 255) / 256), dim3(256),
                       0, stream, w_off, w_mod, w_reg, ws);
    hipLaunchKernelGGL(conv_mfma, dim3(Ww / 16, Hh / 4, Bn), dim3(256),
                       0, stream, x, guide, ws, b_off, b_mod, ws + PAR_OFF);
    hipLaunchKernelGGL(deform_mfma, dim3(Ww / 16, Hh / 4, Bn), dim3(256),
                       0, stream, x, ws, ws + PAR_OFF, out);
}

// Round 6
// 159.733 us; speedup vs baseline: 1.0737x; 1.0737x over previous
//
#include <hip/hip_runtime.h>
#include <math.h>

// Problem constants
#define Bn   4
#define Cc   64
#define Hh   128
#define Ww   128
#define Oo   64
#define HW   16384
#define NPAR 27

// Workspace layout (float offsets)
#define WB2_OFF 0        // bf16 AT2[t][cc][mt2][lane64][8] = 36864 shorts
#define WB_OFF  18432    // bf16 ATd[t][h][mt4][lane64][8]  = 36864 shorts
#define PAR_OFF 36864    // f32 par[B][27][HW]

typedef __attribute__((ext_vector_type(8))) short bf16x8;
typedef __attribute__((ext_vector_type(4))) short s16x4;
typedef __attribute__((ext_vector_type(4))) float f32x4;
typedef __attribute__((ext_vector_type(2), aligned(4))) float f32x2u;

__device__ __forceinline__ short f2bf(float f) {
    unsigned u = __builtin_bit_cast(unsigned, f);
    u += 0x7FFFu + ((u >> 16) & 1u);        // RNE
    return (short)(u >> 16);
}

// ---------------------------------------------------------------------------
// prep: pre-transpose weights into MFMA A-fragment order (coalesced dwordx4
// reads in the main kernels). K reordered tap-major; see r4 comment.
// ---------------------------------------------------------------------------
__global__ void prep_weights(const float* __restrict__ w_off,
                             const float* __restrict__ w_mod,
                             const float* __restrict__ w_reg,
                             float* __restrict__ ws) {
    int i = blockIdx.x * 256 + threadIdx.x;
    short* at2 = (short*)(ws + WB2_OFF);
    short* atd = (short*)(ws + WB_OFF);
    if (i < 36864) {
        int j = i & 7, l = (i >> 3) & 63, mt = (i >> 9) & 1, cc = (i >> 10) & 3, t = i >> 12;
        int lm = l & 15, quad = l >> 4;
        int row = mt * 16 + lm;
        int c = cc * 32 + quad * 8 + j;
        float v = 0.f;
        if (row < 18)      v = w_off[row * 1152 + c * 9 + t];
        else if (row < 27) v = w_mod[(row - 18) * 1152 + c * 9 + t];
        at2[i] = f2bf(v);
    } else if (i < 73728) {
        int e = i - 36864;
        int j = e & 7, l = (e >> 3) & 63, mt = (e >> 9) & 3, h = (e >> 11) & 1, t = e >> 12;
        int lm = l & 15, quad = l >> 4;
        int o = mt * 16 + lm;
        int c = h * 32 + quad * 8 + j;
        atd[e] = f2bf(w_reg[o * 576 + c * 9 + t]);
    }
}

// ---------------------------------------------------------------------------
// conv_mfma (unchanged from r4): barrier-free direct conv, bf16 channel-inner
// window [pos][128ch+8], one ds_read_b128 per B-fragment, coalesced A.
// 39.2KB LDS -> 4 blocks/CU.
// ---------------------------------------------------------------------------
#define CPSTR 136   // bf16 elems per position: 128 ch + 8 pad

__global__ __launch_bounds__(256, 4)
void conv_mfma(const float* __restrict__ x, const float* __restrict__ g,
               const float* __restrict__ ws_,
               const float* __restrict__ b_off, const float* __restrict__ b_mod,
               float* __restrict__ parw) {
    __shared__ __align__(16) short Wd[144 * CPSTR];   // 39168 B

    const int tid = threadIdx.x;
    const int l = tid & 63, lm = l & 15, quad = l >> 4;
    const int w = __builtin_amdgcn_readfirstlane(tid >> 6);   // wave = pixel row
    const int b = blockIdx.z;
    const int ho0 = blockIdx.y * 4, wo0 = blockIdx.x * 16;
    const int row_base = ho0 - 1;     // may be -1: halo rows zero-filled
    const int col_base = wo0 - 4;     // 4-aligned; halo cols zero-filled

    const short* at2 = (const short*)(ws_ + WB2_OFF);
    const float* xb = x + ((size_t)(b * Cc) << 14);
    const float* gb = g + ((size_t)(b * Cc) << 14);

    for (int s = tid; s < 1152; s += 256) {
        int pq = s >> 5, cq = s & 31;
        int r = pq / 6, c4 = (pq - r * 6) * 4;
        int row = row_base + r, col = col_base + c4;
        bool ok = ((unsigned)row < 128u) && ((unsigned)col < 128u);
        f32x4 v0, v1, v2, v3;
        {
            int ch = cq * 4;
            const float* p0 = (ch < Cc) ? (xb + ((size_t)ch << 14)) : (gb + ((size_t)(ch - Cc) << 14));
            const float* p1 = (ch + 1 < Cc) ? (xb + ((size_t)(ch + 1) << 14)) : (gb + ((size_t)(ch + 1 - Cc) << 14));
            const float* p2 = (ch + 2 < Cc) ? (xb + ((size_t)(ch + 2) << 14)) : (gb + ((size_t)(ch + 2 - Cc) << 14));
            const float* p3 = (ch + 3 < Cc) ? (xb + ((size_t)(ch + 3) << 14)) : (gb + ((size_t)(ch + 3 - Cc) << 14));
            f32x4 zz = {0.f, 0.f, 0.f, 0.f};
            size_t off = ((size_t)(row << 7) + col);
            v0 = ok ? *(const f32x4*)(p0 + off) : zz;
            v1 = ok ? *(const f32x4*)(p1 + off) : zz;
            v2 = ok ? *(const f32x4*)(p2 + off) : zz;
            v3 = ok ? *(const f32x4*)(p3 + off) : zz;
        }
#pragma unroll
        for (int p = 0; p < 4; p++) {
            s16x4 o4 = { f2bf(v0[p]), f2bf(v1[p]), f2bf(v2[p]), f2bf(v3[p]) };
            *(s16x4*)&Wd[(r * 24 + c4 + p) * CPSTR + cq * 4] = o4;
        }
    }
    __syncthreads();   // the ONLY barrier

    f32x4 acc0 = {0.f, 0.f, 0.f, 0.f}, acc1 = {0.f, 0.f, 0.f, 0.f};
#pragma unroll
    for (int t = 0; t < 9; t++) {
        int dy = t / 3, dx = t - dy * 3;
        int pos = (w + dy) * 24 + (lm + dx + 3);    // in-window coords, no masks
#pragma unroll
        for (int cc = 0; cc < 4; cc++) {
            bf16x8 bfr = *(const bf16x8*)&Wd[pos * CPSTR + cc * 32 + quad * 8];
            bf16x8 a0 = *(const bf16x8*)(at2 + t * 4096 + cc * 1024 + l * 8);
            bf16x8 a1 = *(const bf16x8*)(at2 + t * 4096 + cc * 1024 + 512 + l * 8);
            acc0 = __builtin_amdgcn_mfma_f32_16x16x32_bf16(a0, bfr, acc0, 0, 0, 0);
            acc1 = __builtin_amdgcn_mfma_f32_16x16x32_bf16(a1, bfr, acc1, 0, 0, 0);
        }
    }

    // Epilogue: D[row j][col lm] -> par channels, fused bias/coords/sigmoid
    const int ho = ho0 + w, wo = wo0 + lm;
    const int pix = (ho << 7) + wo;
    float* par = parw + (size_t)b * NPAR * HW + pix;
#pragma unroll
    for (int mt = 0; mt < 2; mt++) {
        f32x4 a = mt ? acc1 : acc0;
#pragma unroll
        for (int reg = 0; reg < 4; reg++) {
            int j = mt * 16 + quad * 4 + reg;
            float v = a[reg];
            if (j < 18) {
                int k = j >> 1;
                float vb = v + b_off[j];
                if (j & 1) par[(size_t)(9 + k) * HW] = vb + (float)(k - (k / 3) * 3 + wo - 1);
                else       par[(size_t)k * HW]       = vb + (float)(k / 3 + ho - 1);
            } else if (j < 27) {
                int k = j - 18;
                par[(size_t)(18 + k) * HW] = 2.f / (1.f + __expf(-(v + b_mod[k])));
            }
        }
    }
}

// ---------------------------------------------------------------------------
// Per-tap bilinear params from par, fully inline. Same math as r3/r4/r5 ->
// numerics unchanged. Weight outputs DCE'd when caller only uses coords.
// ---------------------------------------------------------------------------
__device__ __forceinline__ void bil_par(const float* __restrict__ par, int pix, int k,
                                        float& wa0, float& wb0, float& wa1, float& wb1,
                                        int& cy0, int& cy1, int& bx2) {
    float py = par[(size_t)k * HW + pix];
    float px = par[(size_t)(9 + k) * HW + pix];
    float m  = par[(size_t)(18 + k) * HW + pix];
    float fy = floorf(py), fx = floorf(px);
    int y0 = (int)fy, x0 = (int)fx;
    int y1 = y0 + 1;
    float wy1 = py - fy, wx1 = px - fx;
    float wy0 = 1.f - wy1, wx0 = 1.f - wx1;
    bool vy0 = (unsigned)y0 < 128u, vy1 = (unsigned)y1 < 128u;
    bool vx0 = (unsigned)x0 < 128u, vx1 = (unsigned)(x0 + 1) < 128u;
    cy0 = min(max(y0, 0), 127); cy1 = min(max(y1, 0), 127);
    bx2 = min(max(x0, 0), 126);
    bool sel_lo = (x0 < 0), sel_hi = (x0 > 126);
    float w00 = (vy0 && vx0) ? wy0 * wx0 * m : 0.f;
    float w01 = (vy0 && vx1) ? wy0 * wx1 * m : 0.f;
    float w10 = (vy1 && vx0) ? wy1 * wx0 * m : 0.f;
    float w11 = (vy1 && vx1) ? wy1 * wx1 * m : 0.f;
    // fold boundary handling into pair weights: wa->[bx2], wb->[bx2+1]
    wa0 = sel_lo ? w01 : (sel_hi ? 0.f : w00);
    wb0 = sel_hi ? w00 : (sel_lo ? 0.f : w01);
    wa1 = sel_lo ? w11 : (sel_hi ? 0.f : w10);
    wb1 = sel_hi ? w10 : (sel_lo ? 0.f : w11);
}

// ---------------------------------------------------------------------------
// deform_mfma round 6: occupancy fix WITHOUT storage. r5's per-lane param
// arrays went to SCRATCH (WRITE_SIZE 16->104MB, VGPR=64 not ~110): failed
// register promotion, every tap re-read params from HBM-backed scratch ->
// 53.7 -> 68us. Fix: store NOTHING. Params are ~25 VALU ops from 3 coalesced
// par loads (VALU is 14% busy); recompute them inline per tap, per half.
// Prologue does a coords-only pass for the in-halo vote (weights DCE'd).
// LDS stays 34.6KB -> 4 blocks/CU; grid 1024 = one full resident wave, no
// straggler tail (r4's 23%-occupancy disease). No arrays -> nothing to spill.
// ---------------------------------------------------------------------------
#define DPSTR 36   // f32 per position: 32 ch + 4 pad

__global__ __launch_bounds__(256, 4)
void deform_mfma(const float* __restrict__ x, const float* __restrict__ ws_,
                 const float* __restrict__ par_base, float* __restrict__ out) {
    __shared__ __align__(16) float Xw[240 * DPSTR];   // 34560 B
    __shared__ int sOk;

    const int tid = threadIdx.x;
    const int l = tid & 63, lm = l & 15, quad = l >> 4;
    const int w = __builtin_amdgcn_readfirstlane(tid >> 6);   // wave = pixel row
    const int b = blockIdx.z;

    const int ho0 = blockIdx.y * 4, wo0 = blockIdx.x * 16;
    const int rb = min(max(ho0 - 3, 0), 128 - 10);
    const int cb = min(max(wo0 - 4, 0), 128 - 24);    // 4-aligned

    const float* par = par_base + (size_t)b * NPAR * HW;
    const short* atd = (const short*)(ws_ + WB_OFF);
    const float* xb  = x + ((size_t)(b * Cc) << 14);

    if (tid == 0) sOk = 1;
    __syncthreads();

    const int pix = ((ho0 + w) << 7) + (wo0 + lm);    // lane's own pixel

    // Prologue vote: coords-only (weight math DCE'd), no storage.
    {
        int okAll = 1;
#pragma unroll
        for (int k = 0; k < 9; k++) {
            float wa0, wb0, wa1, wb1; int cy0, cy1, bx2;
            bil_par(par, pix, k, wa0, wb0, wa1, wb1, cy0, cy1, bx2);
            bool in = ((unsigned)(cy0 - rb) <= 9u) &&
                      ((unsigned)(cy1 - rb) <= 9u) &&
                      ((unsigned)(bx2 - cb) <= 22u);
            okAll &= (int)in;
        }
        if (!okAll) sOk = 0;
    }

    // window stage: 60 pos-quads x 8 ch-quads; 4 f32x4 loads + transpose +
    // 4 f32x4 ds_writes, ch-inner. All positions in-image (bases clamped).
    auto STAGE = [&](int h) {
        for (int s = tid; s < 480; s += 256) {
            int pq = s >> 3, cq = s & 7;
            int r = pq / 6, c4 = (pq - r * 6) * 4;
            size_t off = (size_t)((rb + r) << 7) + cb + c4;
            f32x4 v0 = *(const f32x4*)(xb + ((size_t)(h * 32 + cq * 4 + 0) << 14) + off);
            f32x4 v1 = *(const f32x4*)(xb + ((size_t)(h * 32 + cq * 4 + 1) << 14) + off);
            f32x4 v2 = *(const f32x4*)(xb + ((size_t)(h * 32 + cq * 4 + 2) << 14) + off);
            f32x4 v3 = *(const f32x4*)(xb + ((size_t)(h * 32 + cq * 4 + 3) << 14) + off);
#pragma unroll
            for (int p = 0; p < 4; p++) {
                f32x4 o4 = { v0[p], v1[p], v2[p], v3[p] };
                *(f32x4*)&Xw[(r * 24 + c4 + p) * DPSTR + cq * 4] = o4;
            }
        }
    };

    STAGE(0);
    __syncthreads();
    const int fast = sOk;                 // block-uniform

    f32x4 acc[4];
#pragma unroll
    for (int mt = 0; mt < 4; mt++) acc[mt] = (f32x4){0.f, 0.f, 0.f, 0.f};

    auto T_LOOP = [&](int h) {
#pragma unroll
        for (int t = 0; t < 9; t++) {
            float wa0, wb0, wa1, wb1; int cy0, cy1, bx2;
            bil_par(par, pix, t, wa0, wb0, wa1, wb1, cy0, cy1, bx2);
            int tx = bx2 - cb;
            int ia = (cy0 - rb) * 24 + tx;
            int ib = (cy1 - rb) * 24 + tx;
            const float* pa = &Xw[ia * DPSTR + quad * 8];
            const float* pb = &Xw[ib * DPSTR + quad * 8];
            union { short s8[8]; bf16x8 v; } u;
#pragma unroll
            for (int hf = 0; hf < 2; hf++) {
                f32x4 p00 = *(const f32x4*)(pa + hf * 4);
                f32x4 p01 = *(const f32x4*)(pa + DPSTR + hf * 4);
                f32x4 p10 = *(const f32x4*)(pb + hf * 4);
                f32x4 p11 = *(const f32x4*)(pb + DPSTR + hf * 4);
#pragma unroll
                for (int j = 0; j < 4; j++)
                    u.s8[hf * 4 + j] = f2bf(wa0 * p00[j] + wb0 * p01[j] +
                                            wa1 * p10[j] + wb1 * p11[j]);
            }
#pragma unroll
            for (int mt = 0; mt < 4; mt++) {
                bf16x8 a = *(const bf16x8*)(atd + t * 4096 + h * 2048 + mt * 512 + l * 8);
                acc[mt] = __builtin_amdgcn_mfma_f32_16x16x32_bf16(a, u.v, acc[mt], 0, 0, 0);
            }
        }
    };

    if (fast) {
        T_LOOP(0);
        __syncthreads();      // all waves done reading half 0
        STAGE(1);
        __syncthreads();
        T_LOOP(1);
    } else {
        // rare fallback: offsets beyond halo -> global bilinear gather
#pragma unroll
        for (int h = 0; h < 2; h++) {
#pragma unroll
            for (int t = 0; t < 9; t++) {
                float wa0, wb0, wa1, wb1; int cy0, cy1, bx2;
                bil_par(par, pix, t, wa0, wb0, wa1, wb1, cy0, cy1, bx2);
                int idx0 = (cy0 << 7) + bx2;
                int idx1 = (cy1 << 7) + bx2;
                union { short s8[8]; bf16x8 v; } u;
#pragma unroll
                for (int j = 0; j < 8; j++) {
                    int c = h * 32 + quad * 8 + j;
                    const float* xc = xb + ((size_t)c << 14);
                    f32x2u q0 = *(const f32x2u*)(xc + idx0);
                    f32x2u q1 = *(const f32x2u*)(xc + idx1);
                    u.s8[j] = f2bf(wa0 * q0.x + wb0 * q0.y + wa1 * q1.x + wb1 * q1.y);
                }
#pragma unroll
                for (int mt = 0; mt < 4; mt++) {
                    bf16x8 a = *(const bf16x8*)(atd + t * 4096 + h * 2048 + mt * 512 + l * 8);
                    acc[mt] = __builtin_amdgcn_mfma_f32_16x16x32_bf16(a, u.v, acc[mt], 0, 0, 0);
                }
            }
        }
    }

    // Epilogue: D[row=quad*4+reg][col=lm]; o = mt*16+row, pixel = (ho0+w, wo0+lm)
    const int wo = wo0 + lm, ho = ho0 + w;
#pragma unroll
    for (int mt = 0; mt < 4; mt++) {
        float* op = out + ((size_t)(b * Oo + mt * 16 + quad * 4) << 14) + (ho << 7) + wo;
#pragma unroll
        for (int reg = 0; reg < 4; reg++)
            op[(size_t)reg << 14] = acc[mt][reg];
    }
}

// ---------------------------------------------------------------------------
extern "C" void kernel_launch(void* const* d_in, const int* in_sizes, int n_in,
                              void* d_out, int out_size, void* d_ws, size_t ws_size,
                              hipStream_t stream) {
    const float* x     = (const float*)d_in[0];
    const float* guide = (const float*)d_in[1];
    const float* w_off = (const float*)d_in[2];
    const float* b_off = (const float*)d_in[3];
    const float* w_mod = (const float*)d_in[4];
    const float* b_mod = (const float*)d_in[5];
    const float* w_reg = (const float*)d_in[6];
    float* out = (float*)d_out;
    float* ws  = (float*)d_ws;

    hipLaunchKernelGGL(prep_weights, dim3((73728 + 255) / 256), dim3(256),
                       0, stream, w_off, w_mod, w_reg, ws);
    hipLaunchKernelGGL(conv_mfma, dim3(Ww / 16, Hh / 4, Bn), dim3(256),
                       0, stream, x, guide, ws, b_off, b_mod, ws + PAR_OFF);
    hipLaunchKernelGGL(deform_mfma, dim3(Ww / 16, Hh / 4, Bn), dim3(256),
                       0, stream, x, ws, ws + PAR_OFF, out);
}